// Round 2
// baseline (111.528 us; speedup 1.0000x reference)
//
#include <hip/hip_runtime.h>

// Problem constants (fixed by the reference): B=512 rows, T=32768, K=64, R=4.
#define T_LEN  32768
#define NTHR   1024      // 32 elems/thread/row; 2 rows per block
#define KSEL   64.0f

// sigmoid via v_exp_f32 + v_rcp_f32 (~1 ulp each; verified absmax 1.5e-05 vs np ref)
__device__ __forceinline__ float fast_sigmoid(float x) {
    return __builtin_amdgcn_rcpf(1.0f + __expf(-x));
}

// a * min(2/(1+a+b), 1):  2/(1+s) >= 1  <=>  s <= 1
__device__ __forceinline__ float damp(float a, float b) {
    float s = a + b;
    float f = (s > 1.0f) ? 2.0f * __builtin_amdgcn_rcpf(1.0f + s) : 1.0f;
    return a * f;
}

// sigmoid in place + per-thread sum/max
__device__ __forceinline__ void sigmoid_stat(float4 (&s)[8], float inv_temp,
                                             float& sum, float& mx) {
    sum = 0.0f; mx = 0.0f;
    #pragma unroll
    for (int k = 0; k < 8; ++k) {
        s[k].x = fast_sigmoid(s[k].x * inv_temp);
        s[k].y = fast_sigmoid(s[k].y * inv_temp);
        s[k].z = fast_sigmoid(s[k].z * inv_temp);
        s[k].w = fast_sigmoid(s[k].w * inv_temp);
        sum += (s[k].x + s[k].y) + (s[k].z + s[k].w);
        mx = fmaxf(mx, fmaxf(fmaxf(s[k].x, s[k].y), fmaxf(s[k].z, s[k].w)));
    }
}

// Slow path (block-uniform, correct for any input; never taken for bench data):
// per-thread contiguous 2x16-output windows, re-read + damp with wraparound halo.
__device__ __forceinline__ void slow_row(const float* __restrict__ srow,
                                         float* __restrict__ orow,
                                         float inv_temp, float scale, int tid) {
    #pragma unroll
    for (int c = 0; c < 2; ++c) {
        const int col0 = 32 * tid + 16 * c;
        float w[26];
        #pragma unroll
        for (int j = 0; j < 26; ++j)
            w[j] = fast_sigmoid(srow[(col0 + j) & (T_LEN - 1)] * inv_temp) * scale;
        #pragma unroll
        for (int j = 0; j < 25; ++j) w[j] = damp(w[j], w[j + 1]);
        #pragma unroll
        for (int j = 0; j < 23; ++j) w[j] = damp(w[j], w[j + 2]);
        #pragma unroll
        for (int j = 0; j < 20; ++j) w[j] = damp(w[j], w[j + 3]);
        #pragma unroll
        for (int j = 0; j < 16; ++j) w[j] = damp(w[j], w[j + 4]);
        if (col0 == 0) w[0] = 0.0f;
        float4* q4 = (float4*)(orow + col0);
        q4[0] = make_float4(w[0],  w[1],  w[2],  w[3]);
        q4[1] = make_float4(w[4],  w[5],  w[6],  w[7]);
        q4[2] = make_float4(w[8],  w[9],  w[10], w[11]);
        q4[3] = make_float4(w[12], w[13], w[14], w[15]);
    }
}

// Fast-path validity: if rowmax = max(y)*scale <= 0.5 over the whole row, then for
// every pass s = y_i + y_{i+d} <= 1 => factor min(2/(1+s),1) == 1 EXACTLY, and since
// pass outputs equal pass inputs the bound holds inductively for all 4 passes.
// Then out = scale * sigmoid(scores/temp) elementwise -- no neighbor windows.

// 2 rows per block, software-pipelined:
//  - all 16 float4 loads (rows A and B) issued up front: row-B reads in flight
//    under row-A sigmoid VALU work
//  - ONE fused 4-wide block reduction (sumA,mxA,sumB,mxB) -> 2 barriers per
//    2 rows instead of 4 (each barrier costs a full vmcnt-drain bubble)
//  - stores A then B back-to-back, no intervening barrier: uninterrupted write
//    stream
// VGPR: 64 data + ~25 misc ~= 90 < 128 cap (1024 thr, 4 waves/EU, 1 block/CU).
__global__ __launch_bounds__(NTHR, 4)
void selector_tworow(const float* __restrict__ scores,
                     const float* __restrict__ log_temp,
                     float* __restrict__ out) {
    const int tid  = threadIdx.x;
    const int rowA = 2 * blockIdx.x;
    const int rowB = rowA + 1;
    const float* sArow = scores + (size_t)rowA * T_LEN;
    const float* sBrow = scores + (size_t)rowB * T_LEN;
    float*       oArow = out    + (size_t)rowA * T_LEN;
    float*       oBrow = out    + (size_t)rowB * T_LEN;

    float t = expf(log_temp[0]);
    const float inv_temp = 1.0f / fminf(fmaxf(t, 0.1f), 10.0f);

    // ---- Phase 1: issue ALL loads (both rows), coalesced lane-contiguous float4 ----
    const float4* pA = (const float4*)sArow;
    const float4* pB = (const float4*)sBrow;
    float4 a[8], b[8];
    #pragma unroll
    for (int k = 0; k < 8; ++k) a[k] = pA[tid + NTHR * k];
    #pragma unroll
    for (int k = 0; k < 8; ++k) b[k] = pB[tid + NTHR * k];

    float sumA, mxA, sumB, mxB;
    sigmoid_stat(a, inv_temp, sumA, mxA);   // overlaps in-flight B loads
    sigmoid_stat(b, inv_temp, sumB, mxB);

    // ---- Fused block reduction: 4 quantities, one LDS round (2 barriers) ----
    #pragma unroll
    for (int off = 32; off > 0; off >>= 1) {
        sumA += __shfl_down(sumA, off, 64);
        mxA   = fmaxf(mxA, __shfl_down(mxA, off, 64));
        sumB += __shfl_down(sumB, off, 64);
        mxB   = fmaxf(mxB, __shfl_down(mxB, off, 64));
    }
    __shared__ float4 red[NTHR / 64 + 1];
    const int wid = tid >> 6, lane = tid & 63;
    if (lane == 0) red[wid] = make_float4(sumA, mxA, sumB, mxB);
    __syncthreads();
    if (tid == 0) {
        float4 t4 = red[0];
        #pragma unroll
        for (int i = 1; i < NTHR / 64; ++i) {
            float4 r = red[i];
            t4.x += r.x;  t4.y = fmaxf(t4.y, r.y);
            t4.z += r.z;  t4.w = fmaxf(t4.w, r.w);
        }
        red[NTHR / 64] = t4;
    }
    __syncthreads();
    const float4 tot = red[NTHR / 64];

    const float scaleA = fminf(KSEL / fmaxf(tot.x, 1e-6f), 1.0f);
    const float scaleB = fminf(KSEL / fmaxf(tot.z, 1e-6f), 1.0f);

    // ---- Row A output ----
    if (tot.y * scaleA <= 0.5f) {
        #pragma unroll
        for (int k = 0; k < 8; ++k) {
            a[k].x *= scaleA; a[k].y *= scaleA; a[k].z *= scaleA; a[k].w *= scaleA;
        }
        if (tid == 0) a[0].x = 0.0f;   // y[:,0] = 0 (column 0 lives in lane 0, k=0)
        float4* q4 = (float4*)oArow;
        #pragma unroll
        for (int k = 0; k < 8; ++k) q4[tid + NTHR * k] = a[k];
    } else {
        slow_row(sArow, oArow, inv_temp, scaleA, tid);
    }

    // ---- Row B output (back-to-back with A; no barrier between) ----
    if (tot.w * scaleB <= 0.5f) {
        #pragma unroll
        for (int k = 0; k < 8; ++k) {
            b[k].x *= scaleB; b[k].y *= scaleB; b[k].z *= scaleB; b[k].w *= scaleB;
        }
        if (tid == 0) b[0].x = 0.0f;
        float4* q4 = (float4*)oBrow;
        #pragma unroll
        for (int k = 0; k < 8; ++k) q4[tid + NTHR * k] = b[k];
    } else {
        slow_row(sBrow, oBrow, inv_temp, scaleB, tid);
    }
}

extern "C" void kernel_launch(void* const* d_in, const int* in_sizes, int n_in,
                              void* d_out, int out_size, void* d_ws, size_t ws_size,
                              hipStream_t stream) {
    const float* scores = (const float*)d_in[0];
    const float* lt     = (const float*)d_in[1];
    float*       out    = (float*)d_out;
    const int B = in_sizes[0] / T_LEN;   // 512 rows
    selector_tworow<<<B / 2, NTHR, 0, stream>>>(scores, lt, out);
}